// Round 1
// baseline (865.881 us; speedup 1.0000x reference)
//
#include <hip/hip_runtime.h>
#include <hip/hip_bf16.h>

typedef __bf16 bf16_t;
typedef __bf16 bf16x8 __attribute__((ext_vector_type(8)));
typedef __bf16 bf16x4 __attribute__((ext_vector_type(4)));
typedef float f32x4 __attribute__((ext_vector_type(4)));

// ---------------------------------------------------------------------------
// Sizes (fixed for this problem)
//   B = 16384, D = H = 512
//   A_big : [B][2048] bf16 = [x_re | x_im | h_re | h_im]
//   W1t   : [3072][2048] bf16 (B^T layout, N-major). Columns (n):
//             [0,1024)    : gate z, interleaved re/im (n even = re), K = 2048
//             [1024,2048) : gate r, interleaved,                  K = 2048
//             [2048,3072) : px2,    interleaved,                  K = 1024 (x part only)
//   W2t   : [1024][1024] bf16, ph columns interleaved re/im, K = 1024 over [rh_re | rh_im]
//   A2    : [B][1024] bf16 = [rh_re | rh_im]
//   zbuf  : [B][1024] fp32, interleaved re/im
//   t (= px2 + bx2 + bh2) is staged in d_out, then overwritten by the final result.
// ---------------------------------------------------------------------------

__device__ __forceinline__ void gl_lds16(const bf16_t* g, bf16_t* l) {
  __builtin_amdgcn_global_load_lds(
      (const __attribute__((address_space(1))) void*)g,
      (__attribute__((address_space(3))) void*)l, 16, 0, 0);
}

__device__ __forceinline__ float fast_sigmoid(float x) {
  return 1.0f / (1.0f + __expf(-x));
}

// ---------------------------------------------------------------------------
__global__ void pack_A(const float* __restrict__ x_re, const float* __restrict__ x_im,
                       const float* __restrict__ h_re, const float* __restrict__ h_im,
                       bf16_t* __restrict__ A) {
  int q = blockIdx.x * blockDim.x + threadIdx.x;   // 8388608 quads total
  int i4 = q << 2;
  int b = i4 >> 11;
  int k = i4 & 2047;
  int seg = k >> 9;
  int off = k & 511;
  const float* s = (seg == 0) ? x_re : (seg == 1) ? x_im : (seg == 2) ? h_re : h_im;
  const float4 v = *(const float4*)(s + (size_t)b * 512 + off);
  bf16x4 o = { (bf16_t)v.x, (bf16_t)v.y, (bf16_t)v.z, (bf16_t)v.w };
  *(bf16x4*)(A + (size_t)b * 2048 + k) = o;
}

// ---------------------------------------------------------------------------
__global__ void pack_W(const float* __restrict__ Wx_re, const float* __restrict__ Wx_im,
                       const float* __restrict__ Wh_re, const float* __restrict__ Wh_im,
                       bf16_t* __restrict__ W1t, bf16_t* __restrict__ W2t) {
  int q = blockIdx.x * blockDim.x + threadIdx.x;   // 1572864 quads total
  int n, k2, g, j, p;
  const float *Wre, *Wim;
  bf16_t* dst;
  if (q < 1048576) {                       // W1t rows [0,2048): z and r, k2 in [0,2048)
    n = q >> 9; k2 = (q & 511) << 2;
    g = n >> 10; j = (n & 1023) >> 1; p = n & 1;
    int pair = k2 >> 10;                   // 0: x-part (Wx), 1: h-part (Wh)
    Wre = pair ? Wh_re : Wx_re;
    Wim = pair ? Wh_im : Wx_im;
    dst = W1t + (size_t)n * 2048 + k2;
  } else if (q < 1048576 + 262144) {       // W1t rows [2048,3072): px2, k2 in [0,1024)
    int q2 = q - 1048576;
    n = 2048 + (q2 >> 8); k2 = (q2 & 255) << 2;
    g = 2; j = (n - 2048) >> 1; p = n & 1;
    Wre = Wx_re; Wim = Wx_im;
    dst = W1t + (size_t)n * 2048 + k2;
  } else {                                 // W2t rows [0,1024), k2 in [0,1024)
    int q3 = q - (1048576 + 262144);
    n = q3 >> 8; k2 = (q3 & 255) << 2;
    g = 2; j = n >> 1; p = n & 1;
    Wre = Wh_re; Wim = Wh_im;
    dst = W2t + (size_t)n * 1024 + k2;
  }
  int klocal = k2 & 1023;
  int half = klocal >> 9;                  // 0: real-operand half, 1: imag-operand half
  int off = klocal & 511;
  size_t sidx = ((size_t)g * 512 + j) * 512 + off;
  const float* s = (half == 0) ? (p ? Wim : Wre) : (p ? Wre : Wim);
  float sgn = (half == 1 && p == 0) ? -1.0f : 1.0f;
  float4 v = *(const float4*)(s + sidx);
  bf16x4 o = { (bf16_t)(sgn * v.x), (bf16_t)(sgn * v.y),
               (bf16_t)(sgn * v.z), (bf16_t)(sgn * v.w) };
  *(bf16x4*)dst = o;
}

// ---------------------------------------------------------------------------
// m97-style 128x128 GEMM, BK=32, 256 threads (4 waves, 2x2 of 64x64 subtiles),
// global_load_lds width 16, XOR-swizzled LDS chunks, mfma_f32_16x16x32_bf16.
// MODE 1: fused z/r/px2 epilogue.  MODE 2: fused final (polar-tanh + combine).
template <int MODE>
__launch_bounds__(256)
__global__ void gemm_fused(const bf16_t* __restrict__ A, const bf16_t* __restrict__ W,
                           int LDA, int LDW, int nTiles,
                           float* __restrict__ zbuf, bf16_t* __restrict__ A2,
                           float* __restrict__ outbuf,
                           const float* __restrict__ h_re, const float* __restrict__ h_im,
                           const float* __restrict__ bx_re, const float* __restrict__ bx_im,
                           const float* __restrict__ bh_re, const float* __restrict__ bh_im) {
  __shared__ __align__(16) bf16_t As[128 * 32];
  __shared__ __align__(16) bf16_t Bs[128 * 32];

  const int bid = blockIdx.x;
  const int ntile = bid % nTiles;
  const int mtile = bid / nTiles;
  const int m0 = mtile * 128;
  const int n0 = ntile * 128;
  const int region = (MODE == 1) ? (n0 >> 10) : 0;      // 0:z 1:r 2:px2
  const int KEND = (MODE == 1) ? ((region < 2) ? 2048 : 1024) : 1024;

  const int tid = threadIdx.x;
  const int lane = tid & 63;
  const int w = tid >> 6;

  // staging: 512 16B-chunks per tile, 2 passes of 256 threads
  const int j0 = tid, j1 = tid + 256;
  const int r0 = j0 >> 2, c0 = j0 & 3;
  const int r1 = j1 >> 2, c1 = j1 & 3;
  const int cs0 = c0 ^ (r0 & 3), cs1 = c1 ^ (r1 & 3);   // XOR swizzle (write side)

  const bf16_t* Arow0 = A + (size_t)(m0 + r0) * LDA + cs0 * 8;
  const bf16_t* Arow1 = A + (size_t)(m0 + r1) * LDA + cs1 * 8;
  const bf16_t* Wrow0 = W + (size_t)(n0 + r0) * LDW + cs0 * 8;
  const bf16_t* Wrow1 = W + (size_t)(n0 + r1) * LDW + cs1 * 8;
  bf16_t* lA0 = As + j0 * 8;
  bf16_t* lA1 = As + j1 * 8;
  bf16_t* lB0 = Bs + j0 * 8;
  bf16_t* lB1 = Bs + j1 * 8;

  const int wm = (w >> 1) * 64, wn = (w & 1) * 64;
  const int quad = lane >> 4, lrow = lane & 15;

  // fragment LDS addresses (read side of the swizzle)
  const bf16_t* aAddr[4];
  const bf16_t* bAddr[4];
#pragma unroll
  for (int mt = 0; mt < 4; ++mt) {
    int r = wm + mt * 16 + lrow;
    aAddr[mt] = As + r * 32 + (quad ^ (r & 3)) * 8;
    int rn = wn + mt * 16 + lrow;
    bAddr[mt] = Bs + rn * 32 + (quad ^ (rn & 3)) * 8;
  }

  f32x4 acc[4][4] = {};

  for (int kk = 0; kk < KEND; kk += 32) {
    gl_lds16(Arow0 + kk, lA0);
    gl_lds16(Arow1 + kk, lA1);
    gl_lds16(Wrow0 + kk, lB0);
    gl_lds16(Wrow1 + kk, lB1);
    __syncthreads();
    bf16x8 af[4], bf[4];
#pragma unroll
    for (int mt = 0; mt < 4; ++mt) af[mt] = *(const bf16x8*)aAddr[mt];
#pragma unroll
    for (int nt = 0; nt < 4; ++nt) bf[nt] = *(const bf16x8*)bAddr[nt];
#pragma unroll
    for (int mt = 0; mt < 4; ++mt)
#pragma unroll
      for (int nt = 0; nt < 4; ++nt)
        acc[mt][nt] = __builtin_amdgcn_mfma_f32_16x16x32_bf16(af[mt], bf[nt], acc[mt][nt], 0, 0, 0);
    __syncthreads();
  }

  // ---- epilogue ----
  // C/D layout: col = lane&15, row = quad*4 + reg  [verified m89/m91]
#pragma unroll
  for (int mt = 0; mt < 4; ++mt) {
#pragma unroll
    for (int nt = 0; nt < 4; ++nt) {
#pragma unroll
      for (int rg = 0; rg < 4; ++rg) {
        const int m = m0 + wm + mt * 16 + quad * 4 + rg;
        const int n = n0 + wn + nt * 16 + lrow;
        float v = acc[mt][nt][rg];
        const int p = n & 1;               // 0 = real component, 1 = imag

        if (MODE == 1) {
          const int cj = n & 1023;
          const int j = cj >> 1;
          const float bias = p ? (bx_im[region * 512 + j] + bh_im[region * 512 + j])
                               : (bx_re[region * 512 + j] + bh_re[region * 512 + j]);
          const float val = v + bias;
          if (region == 0) {               // z gate
            zbuf[(size_t)m * 1024 + cj] = fast_sigmoid(val);
          } else if (region == 1) {        // r gate -> rh = r * h (complex)
            float rv = fast_sigmoid(val);
            float ro = __shfl_xor(rv, 1, 64);
            float hp = p ? h_im[(size_t)m * 512 + j] : h_re[(size_t)m * 512 + j];
            float ho = __shfl_xor(hp, 1, 64);
            float rh = (p == 0) ? (rv * hp - ro * ho) : (ro * hp + rv * ho);
            A2[(size_t)m * 1024 + p * 512 + j] = (bf16_t)rh;
          } else {                         // px2 + bx2 + bh2 -> staged in d_out
            outbuf[(size_t)m * 1024 + cj] = val;
          }
        } else {
          // MODE 2: u = t + ph ; h_tilde = tanh(|u|)/|u| * u ; combine
          const int j = n >> 1;
          float t = outbuf[(size_t)m * 1024 + n];
          float u = t + v;
          float uo = __shfl_xor(u, 1, 64);
          float mag = sqrtf(u * u + uo * uo);
          float mm = fminf(mag, 20.0f);
          float e = __expf(2.0f * mm);
          float th = (e - 1.0f) / (e + 1.0f);
          float s = (mag == 0.0f) ? 0.0f : (th / mag);
          float hto = s * u;               // own component of h_tilde
          float htd = s * uo;              // other component
          float zv = zbuf[(size_t)m * 1024 + n];
          float zo = __shfl_xor(zv, 1, 64);
          float hp = p ? h_im[(size_t)m * 512 + j] : h_re[(size_t)m * 512 + j];
          float ho = __shfl_xor(hp, 1, 64);
          float res;
          if (p == 0)
            res = (1.0f - zv) * hp + zo * ho + zv * hto - zo * htd;
          else
            res = (1.0f - zo) * hp - zv * ho + zo * hto + zv * htd;
          outbuf[(size_t)m * 1024 + n] = res;
        }
      }
    }
  }
}

// ---------------------------------------------------------------------------
extern "C" void kernel_launch(void* const* d_in, const int* in_sizes, int n_in,
                              void* d_out, int out_size, void* d_ws, size_t ws_size,
                              hipStream_t stream) {
  const float* x_re  = (const float*)d_in[0];
  const float* x_im  = (const float*)d_in[1];
  const float* h_re  = (const float*)d_in[2];
  const float* h_im  = (const float*)d_in[3];
  const float* Wx_re = (const float*)d_in[4];
  const float* Wx_im = (const float*)d_in[5];
  const float* Wh_re = (const float*)d_in[6];
  const float* Wh_im = (const float*)d_in[7];
  const float* bx_re = (const float*)d_in[8];
  const float* bx_im = (const float*)d_in[9];
  const float* bh_re = (const float*)d_in[10];
  const float* bh_im = (const float*)d_in[11];
  float* out = (float*)d_out;

  char* ws = (char*)d_ws;
  bf16_t* A_big = (bf16_t*)(ws);                         // 67108864 B
  bf16_t* W1t   = (bf16_t*)(ws + 67108864);              // 12582912 B
  bf16_t* W2t   = (bf16_t*)(ws + 79691776);              //  2097152 B
  bf16_t* A2    = (bf16_t*)(ws + 81788928);              // 33554432 B
  float*  zbuf  = (float*) (ws + 115343360);             // 67108864 B  (end: 182452224)

  pack_A<<<32768, 256, 0, stream>>>(x_re, x_im, h_re, h_im, A_big);
  pack_W<<<6144, 256, 0, stream>>>(Wx_re, Wx_im, Wh_re, Wh_im, W1t, W2t);
  gemm_fused<1><<<128 * 24, 256, 0, stream>>>(A_big, W1t, 2048, 2048, 24,
      zbuf, A2, out, h_re, h_im, bx_re, bx_im, bh_re, bh_im);
  gemm_fused<2><<<128 * 8, 256, 0, stream>>>(A2, W2t, 1024, 1024, 8,
      zbuf, A2, out, h_re, h_im, bx_re, bx_im, bh_re, bh_im);
}

// Round 2
// 824.958 us; speedup vs baseline: 1.0496x; 1.0496x over previous
//
#include <hip/hip_runtime.h>
#include <hip/hip_bf16.h>

typedef __bf16 bf16_t;
typedef __bf16 bf16x8 __attribute__((ext_vector_type(8)));
typedef __bf16 bf16x4 __attribute__((ext_vector_type(4)));
typedef float f32x4 __attribute__((ext_vector_type(4)));

// ---------------------------------------------------------------------------
// Sizes (fixed): B = 16384, D = H = 512
//   A_big : [B][2048] bf16 = [x_re | x_im | h_re | h_im]
//   W1t   : [3072][2048] bf16 (B^T layout). Columns: [0,1024) z (K=2048),
//           [1024,2048) r (K=2048), [2048,3072) px2 (K=1024). re/im interleaved.
//   W2t   : [1024][1024] bf16, ph columns interleaved, K=1024 over [rh_re|rh_im]
//   A2    : [B][1024] bf16 = [rh_re | rh_im]
//   zbuf  : [B][1024] fp32 interleaved
//   t (= px2+bx2+bh2) staged in d_out, overwritten by final result in GEMM2.
// ---------------------------------------------------------------------------

__device__ __forceinline__ void gl_lds16(const bf16_t* g, bf16_t* l) {
  __builtin_amdgcn_global_load_lds(
      (const __attribute__((address_space(1))) void*)g,
      (__attribute__((address_space(3))) void*)l, 16, 0, 0);
}

__device__ __forceinline__ float fast_sigmoid(float x) {
  return 1.0f / (1.0f + __expf(-x));
}

// ---------------------------------------------------------------------------
__global__ void pack_A(const float* __restrict__ x_re, const float* __restrict__ x_im,
                       const float* __restrict__ h_re, const float* __restrict__ h_im,
                       bf16_t* __restrict__ A) {
  int q = blockIdx.x * blockDim.x + threadIdx.x;   // 8388608 quads total
  int i4 = q << 2;
  int b = i4 >> 11;
  int k = i4 & 2047;
  int seg = k >> 9;
  int off = k & 511;
  const float* s = (seg == 0) ? x_re : (seg == 1) ? x_im : (seg == 2) ? h_re : h_im;
  const float4 v = *(const float4*)(s + (size_t)b * 512 + off);
  bf16x4 o = { (bf16_t)v.x, (bf16_t)v.y, (bf16_t)v.z, (bf16_t)v.w };
  *(bf16x4*)(A + (size_t)b * 2048 + k) = o;
}

// ---------------------------------------------------------------------------
__global__ void pack_W(const float* __restrict__ Wx_re, const float* __restrict__ Wx_im,
                       const float* __restrict__ Wh_re, const float* __restrict__ Wh_im,
                       bf16_t* __restrict__ W1t, bf16_t* __restrict__ W2t) {
  int q = blockIdx.x * blockDim.x + threadIdx.x;   // 1572864 quads total
  int n, k2, g, j, p;
  const float *Wre, *Wim;
  bf16_t* dst;
  if (q < 1048576) {                       // W1t rows [0,2048): z and r, k2 in [0,2048)
    n = q >> 9; k2 = (q & 511) << 2;
    g = n >> 10; j = (n & 1023) >> 1; p = n & 1;
    int pair = k2 >> 10;                   // 0: x-part (Wx), 1: h-part (Wh)
    Wre = pair ? Wh_re : Wx_re;
    Wim = pair ? Wh_im : Wx_im;
    dst = W1t + (size_t)n * 2048 + k2;
  } else if (q < 1048576 + 262144) {       // W1t rows [2048,3072): px2, k2 in [0,1024)
    int q2 = q - 1048576;
    n = 2048 + (q2 >> 8); k2 = (q2 & 255) << 2;
    g = 2; j = (n - 2048) >> 1; p = n & 1;
    Wre = Wx_re; Wim = Wx_im;
    dst = W1t + (size_t)n * 2048 + k2;
  } else {                                 // W2t rows [0,1024), k2 in [0,1024)
    int q3 = q - (1048576 + 262144);
    n = q3 >> 8; k2 = (q3 & 255) << 2;
    g = 2; j = n >> 1; p = n & 1;
    Wre = Wh_re; Wim = Wh_im;
    dst = W2t + (size_t)n * 1024 + k2;
  }
  int klocal = k2 & 1023;
  int half = klocal >> 9;                  // 0: real-operand half, 1: imag-operand half
  int off = klocal & 511;
  size_t sidx = ((size_t)g * 512 + j) * 512 + off;
  const float* s = (half == 0) ? (p ? Wim : Wre) : (p ? Wre : Wim);
  float sgn = (half == 1 && p == 0) ? -1.0f : 1.0f;
  float4 v = *(const float4*)(s + sidx);
  bf16x4 o = { (bf16_t)(sgn * v.x), (bf16_t)(sgn * v.y),
               (bf16_t)(sgn * v.z), (bf16_t)(sgn * v.w) };
  *(bf16x4*)dst = o;
}

// ---------------------------------------------------------------------------
// 128x128 GEMM, BK=32, 256 threads (4 waves, 2x2 of 64x64 subtiles).
// DOUBLE-BUFFERED LDS: global_load_lds for tile k+1 issued before computing
// tile k; raw s_barrier + asm s_waitcnt vmcnt(0) (m139 pattern) so the drain
// happens while compute runs, not inside the critical path.
// Swizzle: chunk = quad ^ ((row>>1)&3)  -> 2-way LDS bank aliasing (free).
// MODE 1: fused z/r/px2 epilogue.  MODE 2: fused final (polar-tanh + combine).
template <int MODE>
__launch_bounds__(256)
__global__ void gemm_fused(const bf16_t* __restrict__ A, const bf16_t* __restrict__ W,
                           int LDA, int LDW, int nTiles,
                           float* __restrict__ zbuf, bf16_t* __restrict__ A2,
                           float* __restrict__ outbuf,
                           const float* __restrict__ h_re, const float* __restrict__ h_im,
                           const float* __restrict__ bx_re, const float* __restrict__ bx_im,
                           const float* __restrict__ bh_re, const float* __restrict__ bh_im) {
  __shared__ __align__(16) bf16_t As[2][128 * 32];
  __shared__ __align__(16) bf16_t Bs[2][128 * 32];

  const int bid = blockIdx.x;
  const int ntile = bid % nTiles;
  const int mtile = bid / nTiles;
  const int m0 = mtile * 128;
  const int n0 = ntile * 128;
  const int region = (MODE == 1) ? (n0 >> 10) : 0;      // 0:z 1:r 2:px2
  const int KEND = (MODE == 1) ? ((region < 2) ? 2048 : 1024) : 1024;
  const int nIter = KEND >> 5;

  const int tid = threadIdx.x;
  const int lane = tid & 63;
  const int w = tid >> 6;

  // staging: 512 16B-chunks per tile, 2 passes of 256 threads
  const int j0 = tid, j1 = tid + 256;
  const int r0 = j0 >> 2, c0 = j0 & 3;
  const int r1 = j1 >> 2, c1 = j1 & 3;
  const int cs0 = c0 ^ ((r0 >> 1) & 3);                 // swizzle (source side)
  const int cs1 = c1 ^ ((r1 >> 1) & 3);

  const bf16_t* Arow0 = A + (size_t)(m0 + r0) * LDA + cs0 * 8;
  const bf16_t* Arow1 = A + (size_t)(m0 + r1) * LDA + cs1 * 8;
  const bf16_t* Wrow0 = W + (size_t)(n0 + r0) * LDW + cs0 * 8;
  const bf16_t* Wrow1 = W + (size_t)(n0 + r1) * LDW + cs1 * 8;
  const int l0 = j0 * 8, l1 = j1 * 8;                   // linear LDS chunks (gl_lds req)

  const int wm = (w >> 1) * 64, wn = (w & 1) * 64;
  const int quad = lane >> 4, lrow = lane & 15;

  // fragment LDS element offsets (read side of the swizzle)
  int aOff[4], bOff[4];
#pragma unroll
  for (int mt = 0; mt < 4; ++mt) {
    int r = wm + mt * 16 + lrow;
    aOff[mt] = r * 32 + (quad ^ ((r >> 1) & 3)) * 8;
    int rn = wn + mt * 16 + lrow;
    bOff[mt] = rn * 32 + (quad ^ ((rn >> 1) & 3)) * 8;
  }

  f32x4 acc[4][4] = {};

  // prologue: stage tile 0 into buffer 0
  gl_lds16(Arow0, &As[0][l0]);
  gl_lds16(Arow1, &As[0][l1]);
  gl_lds16(Wrow0, &Bs[0][l0]);
  gl_lds16(Wrow1, &Bs[0][l1]);

  for (int it = 0; it < nIter; ++it) {
    // wait own staged loads for tile `it`, then converge all waves
    asm volatile("s_waitcnt vmcnt(0)" ::: "memory");
    __builtin_amdgcn_s_barrier();
    // issue tile it+1 into the other buffer (flies during compute below)
    if (it + 1 < nIter) {
      const int nb = (it + 1) & 1;
      const int kk = (it + 1) << 5;
      gl_lds16(Arow0 + kk, &As[nb][l0]);
      gl_lds16(Arow1 + kk, &As[nb][l1]);
      gl_lds16(Wrow0 + kk, &Bs[nb][l0]);
      gl_lds16(Wrow1 + kk, &Bs[nb][l1]);
    }
    // compute tile `it`
    const bf16_t* Ab = As[it & 1];
    const bf16_t* Bb = Bs[it & 1];
    bf16x8 af[4], bfr[4];
#pragma unroll
    for (int mt = 0; mt < 4; ++mt) af[mt] = *(const bf16x8*)(Ab + aOff[mt]);
#pragma unroll
    for (int nt = 0; nt < 4; ++nt) bfr[nt] = *(const bf16x8*)(Bb + bOff[nt]);
#pragma unroll
    for (int mt = 0; mt < 4; ++mt)
#pragma unroll
      for (int nt = 0; nt < 4; ++nt)
        acc[mt][nt] = __builtin_amdgcn_mfma_f32_16x16x32_bf16(af[mt], bfr[nt], acc[mt][nt], 0, 0, 0);
    // NOTE: no trailing barrier needed; next iteration's waitcnt+barrier
    // protects both buffers (compute(it)'s ds_reads are consumed before the
    // wave reaches that barrier, so overwriting buf[(it+2)&1]=buf[it&1] later
    // is safe).
  }

  // ---- epilogue ----
  // C/D layout: col = lane&15, row = quad*4 + reg  [verified m89/m91]
#pragma unroll
  for (int mt = 0; mt < 4; ++mt) {
#pragma unroll
    for (int nt = 0; nt < 4; ++nt) {
#pragma unroll
      for (int rg = 0; rg < 4; ++rg) {
        const int m = m0 + wm + mt * 16 + quad * 4 + rg;
        const int n = n0 + wn + nt * 16 + lrow;
        float v = acc[mt][nt][rg];
        const int p = n & 1;               // 0 = real component, 1 = imag

        if (MODE == 1) {
          const int cj = n & 1023;
          const int j = cj >> 1;
          const float bias = p ? (bx_im[region * 512 + j] + bh_im[region * 512 + j])
                               : (bx_re[region * 512 + j] + bh_re[region * 512 + j]);
          const float val = v + bias;
          if (region == 0) {               // z gate
            zbuf[(size_t)m * 1024 + cj] = fast_sigmoid(val);
          } else if (region == 1) {        // r gate -> rh = r * h (complex)
            float rv = fast_sigmoid(val);
            float ro = __shfl_xor(rv, 1, 64);
            float hp = p ? h_im[(size_t)m * 512 + j] : h_re[(size_t)m * 512 + j];
            float ho = __shfl_xor(hp, 1, 64);
            float rh = (p == 0) ? (rv * hp - ro * ho) : (ro * hp + rv * ho);
            A2[(size_t)m * 1024 + p * 512 + j] = (bf16_t)rh;
          } else {                         // px2 + bx2 + bh2 -> staged in d_out
            outbuf[(size_t)m * 1024 + cj] = val;
          }
        } else {
          // MODE 2: u = t + ph ; h_tilde = tanh(|u|)/|u| * u ; combine
          const int j = n >> 1;
          float t = outbuf[(size_t)m * 1024 + n];
          float u = t + v;
          float uo = __shfl_xor(u, 1, 64);
          float mag = sqrtf(u * u + uo * uo);
          float mm = fminf(mag, 20.0f);
          float e = __expf(2.0f * mm);
          float th = (e - 1.0f) / (e + 1.0f);
          float s = (mag == 0.0f) ? 0.0f : (th / mag);
          float hto = s * u;               // own component of h_tilde
          float htd = s * uo;              // other component
          float zv = zbuf[(size_t)m * 1024 + n];
          float zo = __shfl_xor(zv, 1, 64);
          float hp = p ? h_im[(size_t)m * 512 + j] : h_re[(size_t)m * 512 + j];
          float ho = __shfl_xor(hp, 1, 64);
          float res;
          if (p == 0)
            res = (1.0f - zv) * hp + zo * ho + zv * hto - zo * htd;
          else
            res = (1.0f - zo) * hp - zv * ho + zo * hto + zv * htd;
          outbuf[(size_t)m * 1024 + n] = res;
        }
      }
    }
  }
}

// ---------------------------------------------------------------------------
extern "C" void kernel_launch(void* const* d_in, const int* in_sizes, int n_in,
                              void* d_out, int out_size, void* d_ws, size_t ws_size,
                              hipStream_t stream) {
  const float* x_re  = (const float*)d_in[0];
  const float* x_im  = (const float*)d_in[1];
  const float* h_re  = (const float*)d_in[2];
  const float* h_im  = (const float*)d_in[3];
  const float* Wx_re = (const float*)d_in[4];
  const float* Wx_im = (const float*)d_in[5];
  const float* Wh_re = (const float*)d_in[6];
  const float* Wh_im = (const float*)d_in[7];
  const float* bx_re = (const float*)d_in[8];
  const float* bx_im = (const float*)d_in[9];
  const float* bh_re = (const float*)d_in[10];
  const float* bh_im = (const float*)d_in[11];
  float* out = (float*)d_out;

  char* ws = (char*)d_ws;
  bf16_t* A_big = (bf16_t*)(ws);                         // 67108864 B
  bf16_t* W1t   = (bf16_t*)(ws + 67108864);              // 12582912 B
  bf16_t* W2t   = (bf16_t*)(ws + 79691776);              //  2097152 B
  bf16_t* A2    = (bf16_t*)(ws + 81788928);              // 33554432 B
  float*  zbuf  = (float*) (ws + 115343360);             // 67108864 B  (end: 182452224)

  pack_A<<<32768, 256, 0, stream>>>(x_re, x_im, h_re, h_im, A_big);
  pack_W<<<6144, 256, 0, stream>>>(Wx_re, Wx_im, Wh_re, Wh_im, W1t, W2t);
  gemm_fused<1><<<128 * 24, 256, 0, stream>>>(A_big, W1t, 2048, 2048, 24,
      zbuf, A2, out, h_re, h_im, bx_re, bx_im, bh_re, bh_im);
  gemm_fused<2><<<128 * 8, 256, 0, stream>>>(A2, W2t, 1024, 1024, 8,
      zbuf, A2, out, h_re, h_im, bx_re, bx_im, bh_re, bh_im);
}

// Round 3
// 732.629 us; speedup vs baseline: 1.1819x; 1.1260x over previous
//
#include <hip/hip_runtime.h>
#include <hip/hip_bf16.h>

typedef __bf16 bf16_t;
typedef __bf16 bf16x8 __attribute__((ext_vector_type(8)));
typedef __bf16 bf16x4 __attribute__((ext_vector_type(4)));
typedef float f32x4 __attribute__((ext_vector_type(4)));

// ---------------------------------------------------------------------------
// Sizes (fixed): B = 16384, D = H = 512
//   A_big : [B][2048] bf16 = [x_re | x_im | h_re | h_im]
//   W1t   : [3072][2048] bf16 (B^T layout). Columns: [0,1024) z (K=2048),
//           [1024,2048) r (K=2048), [2048,3072) px2 (K=1024). re/im interleaved.
//   W2t   : [1024][1024] bf16, ph columns interleaved, K=1024 over [rh_re|rh_im]
//   A2    : [B][1024] bf16 = [rh_re | rh_im]
//   zbuf  : [B][1024] fp32 interleaved
//   t (= px2+bx2+bh2) staged in d_out, overwritten by final result in GEMM2.
// ---------------------------------------------------------------------------

__device__ __forceinline__ void gl_lds16(const bf16_t* g, bf16_t* l) {
  __builtin_amdgcn_global_load_lds(
      (const __attribute__((address_space(1))) void*)g,
      (__attribute__((address_space(3))) void*)l, 16, 0, 0);
}

__device__ __forceinline__ float fast_sigmoid(float x) {
  return 1.0f / (1.0f + __expf(-x));
}

// ---------------------------------------------------------------------------
__global__ void pack_A(const float* __restrict__ x_re, const float* __restrict__ x_im,
                       const float* __restrict__ h_re, const float* __restrict__ h_im,
                       bf16_t* __restrict__ A) {
  int q = blockIdx.x * blockDim.x + threadIdx.x;   // 8388608 quads total
  int i4 = q << 2;
  int b = i4 >> 11;
  int k = i4 & 2047;
  int seg = k >> 9;
  int off = k & 511;
  const float* s = (seg == 0) ? x_re : (seg == 1) ? x_im : (seg == 2) ? h_re : h_im;
  const float4 v = *(const float4*)(s + (size_t)b * 512 + off);
  bf16x4 o = { (bf16_t)v.x, (bf16_t)v.y, (bf16_t)v.z, (bf16_t)v.w };
  *(bf16x4*)(A + (size_t)b * 2048 + k) = o;
}

// ---------------------------------------------------------------------------
__global__ void pack_W(const float* __restrict__ Wx_re, const float* __restrict__ Wx_im,
                       const float* __restrict__ Wh_re, const float* __restrict__ Wh_im,
                       bf16_t* __restrict__ W1t, bf16_t* __restrict__ W2t) {
  int q = blockIdx.x * blockDim.x + threadIdx.x;   // 1572864 quads total
  int n, k2, g, j, p;
  const float *Wre, *Wim;
  bf16_t* dst;
  if (q < 1048576) {                       // W1t rows [0,2048): z and r, k2 in [0,2048)
    n = q >> 9; k2 = (q & 511) << 2;
    g = n >> 10; j = (n & 1023) >> 1; p = n & 1;
    int pair = k2 >> 10;                   // 0: x-part (Wx), 1: h-part (Wh)
    Wre = pair ? Wh_re : Wx_re;
    Wim = pair ? Wh_im : Wx_im;
    dst = W1t + (size_t)n * 2048 + k2;
  } else if (q < 1048576 + 262144) {       // W1t rows [2048,3072): px2, k2 in [0,1024)
    int q2 = q - 1048576;
    n = 2048 + (q2 >> 8); k2 = (q2 & 255) << 2;
    g = 2; j = (n - 2048) >> 1; p = n & 1;
    Wre = Wx_re; Wim = Wx_im;
    dst = W1t + (size_t)n * 2048 + k2;
  } else {                                 // W2t rows [0,1024), k2 in [0,1024)
    int q3 = q - (1048576 + 262144);
    n = q3 >> 8; k2 = (q3 & 255) << 2;
    g = 2; j = n >> 1; p = n & 1;
    Wre = Wh_re; Wim = Wh_im;
    dst = W2t + (size_t)n * 1024 + k2;
  }
  int klocal = k2 & 1023;
  int half = klocal >> 9;                  // 0: real-operand half, 1: imag-operand half
  int off = klocal & 511;
  size_t sidx = ((size_t)g * 512 + j) * 512 + off;
  const float* s = (half == 0) ? (p ? Wim : Wre) : (p ? Wre : Wim);
  float sgn = (half == 1 && p == 0) ? -1.0f : 1.0f;
  float4 v = *(const float4*)(s + sidx);
  bf16x4 o = { (bf16_t)(sgn * v.x), (bf16_t)(sgn * v.y),
               (bf16_t)(sgn * v.z), (bf16_t)(sgn * v.w) };
  *(bf16x4*)dst = o;
}

// ---------------------------------------------------------------------------
// 128x128 GEMM, BK=32, 256 threads (4 waves, 2x2 of 64x64 subtiles).
// 3-stage LDS ring, 2-deep global_load_lds prefetch, steady-state wait is
// s_waitcnt vmcnt(4) (never 0), raw s_barrier. __launch_bounds__(256,3)
// forces <=170 total regs -> 3 blocks/CU. XCD-aware tile swizzle: each XCD
// band works one 128-col W slab (L2-resident) across all 128 m-tiles.
// MODE 1: fused z/r/px2 epilogue.  MODE 2: fused final (polar-tanh + combine).
template <int MODE>
__launch_bounds__(256, 3)
__global__ void gemm_fused(const bf16_t* __restrict__ A, const bf16_t* __restrict__ W,
                           int LDA, int LDW,
                           float* __restrict__ zbuf, bf16_t* __restrict__ A2,
                           float* __restrict__ outbuf,
                           const float* __restrict__ h_re, const float* __restrict__ h_im,
                           const float* __restrict__ bx_re, const float* __restrict__ bx_im,
                           const float* __restrict__ bh_re, const float* __restrict__ bh_im) {
  __shared__ __align__(16) bf16_t As[3][128 * 32];
  __shared__ __align__(16) bf16_t Bs[3][128 * 32];

  const int bid = blockIdx.x;
  // XCD swizzle: consecutive bids go to different XCDs (round-robin); give
  // each XCD its own ntile band so its W slab (512 KB) stays L2-resident.
  const int grp = bid >> 3;
  const int band = grp >> 7;               // 0..2 (GEMM1) / 0 (GEMM2)
  const int mtile = grp & 127;
  const int ntile = (bid & 7) + band * 8;
  const int m0 = mtile * 128;
  const int n0 = ntile * 128;
  const int region = (MODE == 1) ? (ntile >> 3) : 0;    // 0:z 1:r 2:px2
  const int KEND = (MODE == 1) ? ((region < 2) ? 2048 : 1024) : 1024;
  const int nIter = KEND >> 5;

  const int tid = threadIdx.x;
  const int lane = tid & 63;
  const int w = tid >> 6;

  // staging: 512 16B-chunks per tile, 2 passes of 256 threads
  const int j0 = tid, j1 = tid + 256;
  const int r0 = j0 >> 2, c0 = j0 & 3;
  const int r1 = j1 >> 2, c1 = j1 & 3;
  const int cs0 = c0 ^ ((r0 >> 1) & 3);                 // swizzle (source side)
  const int cs1 = c1 ^ ((r1 >> 1) & 3);

  const bf16_t* Arow0 = A + (size_t)(m0 + r0) * LDA + cs0 * 8;
  const bf16_t* Arow1 = A + (size_t)(m0 + r1) * LDA + cs1 * 8;
  const bf16_t* Wrow0 = W + (size_t)(n0 + r0) * LDW + cs0 * 8;
  const bf16_t* Wrow1 = W + (size_t)(n0 + r1) * LDW + cs1 * 8;
  const int l0 = j0 * 8, l1 = j1 * 8;                   // linear LDS chunks

  const int wm = (w >> 1) * 64, wn = (w & 1) * 64;
  const int quad = lane >> 4, lrow = lane & 15;

  // fragment LDS element offsets (read side of the swizzle)
  int aOff[4], bOff[4];
#pragma unroll
  for (int mt = 0; mt < 4; ++mt) {
    int r = wm + mt * 16 + lrow;
    aOff[mt] = r * 32 + (quad ^ ((r >> 1) & 3)) * 8;
    int rn = wn + mt * 16 + lrow;
    bOff[mt] = rn * 32 + (quad ^ ((rn >> 1) & 3)) * 8;
  }

  f32x4 acc[4][4] = {};

  // prologue: stage tiles 0 and 1 into ring slots 0 and 1
  gl_lds16(Arow0, &As[0][l0]);
  gl_lds16(Arow1, &As[0][l1]);
  gl_lds16(Wrow0, &Bs[0][l0]);
  gl_lds16(Wrow1, &Bs[0][l1]);
  gl_lds16(Arow0 + 32, &As[1][l0]);
  gl_lds16(Arow1 + 32, &As[1][l1]);
  gl_lds16(Wrow0 + 32, &Bs[1][l0]);
  gl_lds16(Wrow1 + 32, &Bs[1][l1]);

  int slot = 0;            // ring slot holding tile `it`
  for (int it = 0; it < nIter; ++it) {
    // wait until tile `it`'s 4 loads are done; tile it+1's may still fly
    if (it + 1 < nIter) {
      asm volatile("s_waitcnt vmcnt(4)" ::: "memory");
    } else {
      asm volatile("s_waitcnt vmcnt(0)" ::: "memory");
    }
    __builtin_amdgcn_s_barrier();
    // issue tile it+2 into the slot freed by tile it-1
    if (it + 2 < nIter) {
      int ns = slot + 2; if (ns >= 3) ns -= 3;
      const int kk = (it + 2) << 5;
      gl_lds16(Arow0 + kk, &As[ns][l0]);
      gl_lds16(Arow1 + kk, &As[ns][l1]);
      gl_lds16(Wrow0 + kk, &Bs[ns][l0]);
      gl_lds16(Wrow1 + kk, &Bs[ns][l1]);
    }
    // compute tile `it` (one live A-frag at a time to cap register pressure)
    const bf16_t* Ab = As[slot];
    const bf16_t* Bb = Bs[slot];
    bf16x8 bfr[4];
#pragma unroll
    for (int nt = 0; nt < 4; ++nt) bfr[nt] = *(const bf16x8*)(Bb + bOff[nt]);
#pragma unroll
    for (int mt = 0; mt < 4; ++mt) {
      bf16x8 af = *(const bf16x8*)(Ab + aOff[mt]);
#pragma unroll
      for (int nt = 0; nt < 4; ++nt)
        acc[mt][nt] = __builtin_amdgcn_mfma_f32_16x16x32_bf16(af, bfr[nt], acc[mt][nt], 0, 0, 0);
    }
    ++slot; if (slot >= 3) slot = 0;
  }

  // ---- epilogue ----
  // C/D layout: col = lane&15, row = quad*4 + reg  [verified m89/m91]
#pragma unroll
  for (int mt = 0; mt < 4; ++mt) {
#pragma unroll
    for (int nt = 0; nt < 4; ++nt) {
#pragma unroll
      for (int rg = 0; rg < 4; ++rg) {
        const int m = m0 + wm + mt * 16 + quad * 4 + rg;
        const int n = n0 + wn + nt * 16 + lrow;
        float v = acc[mt][nt][rg];
        const int p = n & 1;               // 0 = real component, 1 = imag

        if (MODE == 1) {
          const int cj = n & 1023;
          const int j = cj >> 1;
          const float bias = p ? (bx_im[region * 512 + j] + bh_im[region * 512 + j])
                               : (bx_re[region * 512 + j] + bh_re[region * 512 + j]);
          const float val = v + bias;
          if (region == 0) {               // z gate
            zbuf[(size_t)m * 1024 + cj] = fast_sigmoid(val);
          } else if (region == 1) {        // r gate -> rh = r * h (complex)
            float rv = fast_sigmoid(val);
            float ro = __shfl_xor(rv, 1, 64);
            float hp = p ? h_im[(size_t)m * 512 + j] : h_re[(size_t)m * 512 + j];
            float ho = __shfl_xor(hp, 1, 64);
            float rh = (p == 0) ? (rv * hp - ro * ho) : (ro * hp + rv * ho);
            A2[(size_t)m * 1024 + p * 512 + j] = (bf16_t)rh;
          } else {                         // px2 + bx2 + bh2 -> staged in d_out
            outbuf[(size_t)m * 1024 + cj] = val;
          }
        } else {
          // MODE 2: u = t + ph ; h_tilde = tanh(|u|)/|u| * u ; combine
          const int j = n >> 1;
          float t = outbuf[(size_t)m * 1024 + n];
          float u = t + v;
          float uo = __shfl_xor(u, 1, 64);
          float mag = sqrtf(u * u + uo * uo);
          float mm = fminf(mag, 20.0f);
          float e = __expf(2.0f * mm);
          float th = (e - 1.0f) / (e + 1.0f);
          float s = (mag == 0.0f) ? 0.0f : (th / mag);
          float hto = s * u;               // own component of h_tilde
          float htd = s * uo;              // other component
          float zv = zbuf[(size_t)m * 1024 + n];
          float zo = __shfl_xor(zv, 1, 64);
          float hp = p ? h_im[(size_t)m * 512 + j] : h_re[(size_t)m * 512 + j];
          float ho = __shfl_xor(hp, 1, 64);
          float res;
          if (p == 0)
            res = (1.0f - zv) * hp + zo * ho + zv * hto - zo * htd;
          else
            res = (1.0f - zo) * hp - zv * ho + zo * hto + zv * htd;
          outbuf[(size_t)m * 1024 + n] = res;
        }
      }
    }
  }
}

// ---------------------------------------------------------------------------
extern "C" void kernel_launch(void* const* d_in, const int* in_sizes, int n_in,
                              void* d_out, int out_size, void* d_ws, size_t ws_size,
                              hipStream_t stream) {
  const float* x_re  = (const float*)d_in[0];
  const float* x_im  = (const float*)d_in[1];
  const float* h_re  = (const float*)d_in[2];
  const float* h_im  = (const float*)d_in[3];
  const float* Wx_re = (const float*)d_in[4];
  const float* Wx_im = (const float*)d_in[5];
  const float* Wh_re = (const float*)d_in[6];
  const float* Wh_im = (const float*)d_in[7];
  const float* bx_re = (const float*)d_in[8];
  const float* bx_im = (const float*)d_in[9];
  const float* bh_re = (const float*)d_in[10];
  const float* bh_im = (const float*)d_in[11];
  float* out = (float*)d_out;

  char* ws = (char*)d_ws;
  bf16_t* A_big = (bf16_t*)(ws);                         // 67108864 B
  bf16_t* W1t   = (bf16_t*)(ws + 67108864);              // 12582912 B
  bf16_t* W2t   = (bf16_t*)(ws + 79691776);              //  2097152 B
  bf16_t* A2    = (bf16_t*)(ws + 81788928);              // 33554432 B
  float*  zbuf  = (float*) (ws + 115343360);             // 67108864 B  (end: 182452224)

  pack_A<<<32768, 256, 0, stream>>>(x_re, x_im, h_re, h_im, A_big);
  pack_W<<<6144, 256, 0, stream>>>(Wx_re, Wx_im, Wh_re, Wh_im, W1t, W2t);
  gemm_fused<1><<<128 * 24, 256, 0, stream>>>(A_big, W1t, 2048, 2048,
      zbuf, A2, out, h_re, h_im, bx_re, bx_im, bh_re, bh_im);
  gemm_fused<2><<<128 * 8, 256, 0, stream>>>(A2, W2t, 1024, 1024,
      zbuf, A2, out, h_re, h_im, bx_re, bx_im, bh_re, bh_im);
}

// Round 4
// 728.688 us; speedup vs baseline: 1.1883x; 1.0054x over previous
//
#include <hip/hip_runtime.h>
#include <hip/hip_bf16.h>

typedef __bf16 bf16_t;
typedef __bf16 bf16x8 __attribute__((ext_vector_type(8)));
typedef __bf16 bf16x4 __attribute__((ext_vector_type(4)));
typedef float f32x4 __attribute__((ext_vector_type(4)));

// ---------------------------------------------------------------------------
// Sizes (fixed): B = 16384, D = H = 512
//   A_big : [B][2048] bf16 = [x_re | x_im | h_re | h_im]
//   W1t   : [3072][2048] bf16 (B^T layout). Columns: [0,1024) z (K=2048),
//           [1024,2048) r (K=2048), [2048,3072) px2 (K=1024). re/im interleaved.
//   W2t   : [1024][1024] bf16, ph columns interleaved, K=1024 over [rh_re|rh_im]
//   A2    : [B][1024] bf16 = [rh_re | rh_im]
//   zbuf  : [B][1024] bf16 interleaved (z in [0,1]; bf16 quant <= 4e-3, safe)
//   t (= px2+bx2+bh2) staged fp32 in d_out, overwritten by final in GEMM2.
// ---------------------------------------------------------------------------

__device__ __forceinline__ void gl_lds16(const bf16_t* g, bf16_t* l) {
  __builtin_amdgcn_global_load_lds(
      (const __attribute__((address_space(1))) void*)g,
      (__attribute__((address_space(3))) void*)l, 16, 0, 0);
}

__device__ __forceinline__ float fast_sigmoid(float x) {
  return 1.0f / (1.0f + __expf(-x));
}

// ---------------------------------------------------------------------------
__global__ void pack_A(const float* __restrict__ x_re, const float* __restrict__ x_im,
                       const float* __restrict__ h_re, const float* __restrict__ h_im,
                       bf16_t* __restrict__ A) {
  int q = blockIdx.x * blockDim.x + threadIdx.x;   // 8388608 quads total
  int i4 = q << 2;
  int b = i4 >> 11;
  int k = i4 & 2047;
  int seg = k >> 9;
  int off = k & 511;
  const float* s = (seg == 0) ? x_re : (seg == 1) ? x_im : (seg == 2) ? h_re : h_im;
  const float4 v = *(const float4*)(s + (size_t)b * 512 + off);
  bf16x4 o = { (bf16_t)v.x, (bf16_t)v.y, (bf16_t)v.z, (bf16_t)v.w };
  *(bf16x4*)(A + (size_t)b * 2048 + k) = o;
}

// ---------------------------------------------------------------------------
__global__ void pack_W(const float* __restrict__ Wx_re, const float* __restrict__ Wx_im,
                       const float* __restrict__ Wh_re, const float* __restrict__ Wh_im,
                       bf16_t* __restrict__ W1t, bf16_t* __restrict__ W2t) {
  int q = blockIdx.x * blockDim.x + threadIdx.x;   // 1572864 quads total
  int n, k2, g, j, p;
  const float *Wre, *Wim;
  bf16_t* dst;
  if (q < 1048576) {                       // W1t rows [0,2048): z and r, k2 in [0,2048)
    n = q >> 9; k2 = (q & 511) << 2;
    g = n >> 10; j = (n & 1023) >> 1; p = n & 1;
    int pair = k2 >> 10;                   // 0: x-part (Wx), 1: h-part (Wh)
    Wre = pair ? Wh_re : Wx_re;
    Wim = pair ? Wh_im : Wx_im;
    dst = W1t + (size_t)n * 2048 + k2;
  } else if (q < 1048576 + 262144) {       // W1t rows [2048,3072): px2, k2 in [0,1024)
    int q2 = q - 1048576;
    n = 2048 + (q2 >> 8); k2 = (q2 & 255) << 2;
    g = 2; j = (n - 2048) >> 1; p = n & 1;
    Wre = Wx_re; Wim = Wx_im;
    dst = W1t + (size_t)n * 2048 + k2;
  } else {                                 // W2t rows [0,1024), k2 in [0,1024)
    int q3 = q - (1048576 + 262144);
    n = q3 >> 8; k2 = (q3 & 255) << 2;
    g = 2; j = n >> 1; p = n & 1;
    Wre = Wh_re; Wim = Wh_im;
    dst = W2t + (size_t)n * 1024 + k2;
  }
  int klocal = k2 & 1023;
  int half = klocal >> 9;                  // 0: real-operand half, 1: imag-operand half
  int off = klocal & 511;
  size_t sidx = ((size_t)g * 512 + j) * 512 + off;
  const float* s = (half == 0) ? (p ? Wim : Wre) : (p ? Wre : Wim);
  float sgn = (half == 1 && p == 0) ? -1.0f : 1.0f;
  float4 v = *(const float4*)(s + sidx);
  bf16x4 o = { (bf16_t)(sgn * v.x), (bf16_t)(sgn * v.y),
               (bf16_t)(sgn * v.z), (bf16_t)(sgn * v.w) };
  *(bf16x4*)dst = o;
}

// ---------------------------------------------------------------------------
// 128x128 GEMM, BK=32, 256 threads (4 waves, 2x2 of 64x64 subtiles).
// 3-stage LDS ring, 2-deep global_load_lds prefetch, steady-state wait
// s_waitcnt vmcnt(4), raw s_barrier. __launch_bounds__(256,3) -> 3 blocks/CU.
// Locality swizzle (MODE 1): 4 phases of 768 blocks; within a phase XCD
// (bid&7) owns ntiles {x, x+8, x+16} (one z/r/px2 each -> uniform work, W
// footprint 1.25 MB L2-resident) x 32 mtiles, so each 512 KB A-slab is read
// by 3 same-XCD blocks (L2) and 8 XCDs within a 16 MB phase window (L3).
// MODE 2: ntile = bid&7 (W2 slab L2-resident), mtile = bid>>3 (lockstep
// mtile sweep across XCDs -> A2 shared via L3).
template <int MODE>
__launch_bounds__(256, 3)
__global__ void gemm_fused(const bf16_t* __restrict__ A, const bf16_t* __restrict__ W,
                           int LDA, int LDW,
                           bf16_t* __restrict__ zbuf, bf16_t* __restrict__ A2,
                           float* __restrict__ outbuf,
                           const float* __restrict__ h_re, const float* __restrict__ h_im,
                           const float* __restrict__ bx_re, const float* __restrict__ bx_im,
                           const float* __restrict__ bh_re, const float* __restrict__ bh_im) {
  __shared__ __align__(16) bf16_t As[3][128 * 32];
  __shared__ __align__(16) bf16_t Bs[3][128 * 32];

  const int bid = blockIdx.x;
  int mtile, ntile;
  if (MODE == 1) {
    const int phase = bid / 768;           // 0..3
    const int i = bid - phase * 768;       // 0..767 (resident cohort)
    const int j = i >> 3;                  // 0..95
    ntile = (i & 7) + ((j % 3) << 3);      // XCD x -> ntiles {x, x+8, x+16}
    mtile = phase * 32 + j / 3;            // 0..127
  } else {
    ntile = bid & 7;
    mtile = bid >> 3;
  }
  const int m0 = mtile * 128;
  const int n0 = ntile * 128;
  const int region = (MODE == 1) ? (ntile >> 3) : 0;    // 0:z 1:r 2:px2
  const int KEND = (MODE == 1) ? ((region < 2) ? 2048 : 1024) : 1024;
  const int nIter = KEND >> 5;

  const int tid = threadIdx.x;
  const int lane = tid & 63;
  const int w = tid >> 6;

  // staging: 512 16B-chunks per tile, 2 passes of 256 threads
  const int j0 = tid, j1 = tid + 256;
  const int r0 = j0 >> 2, c0 = j0 & 3;
  const int r1 = j1 >> 2, c1 = j1 & 3;
  const int cs0 = c0 ^ ((r0 >> 1) & 3);                 // swizzle (source side)
  const int cs1 = c1 ^ ((r1 >> 1) & 3);

  const bf16_t* Arow0 = A + (size_t)(m0 + r0) * LDA + cs0 * 8;
  const bf16_t* Arow1 = A + (size_t)(m0 + r1) * LDA + cs1 * 8;
  const bf16_t* Wrow0 = W + (size_t)(n0 + r0) * LDW + cs0 * 8;
  const bf16_t* Wrow1 = W + (size_t)(n0 + r1) * LDW + cs1 * 8;
  const int l0 = j0 * 8, l1 = j1 * 8;                   // linear LDS chunks

  const int wm = (w >> 1) * 64, wn = (w & 1) * 64;
  const int quad = lane >> 4, lrow = lane & 15;

  // fragment LDS element offsets (read side of the swizzle)
  int aOff[4], bOff[4];
#pragma unroll
  for (int mt = 0; mt < 4; ++mt) {
    int r = wm + mt * 16 + lrow;
    aOff[mt] = r * 32 + (quad ^ ((r >> 1) & 3)) * 8;
    int rn = wn + mt * 16 + lrow;
    bOff[mt] = rn * 32 + (quad ^ ((rn >> 1) & 3)) * 8;
  }

  f32x4 acc[4][4] = {};

  // prologue: stage tiles 0 and 1 into ring slots 0 and 1
  gl_lds16(Arow0, &As[0][l0]);
  gl_lds16(Arow1, &As[0][l1]);
  gl_lds16(Wrow0, &Bs[0][l0]);
  gl_lds16(Wrow1, &Bs[0][l1]);
  gl_lds16(Arow0 + 32, &As[1][l0]);
  gl_lds16(Arow1 + 32, &As[1][l1]);
  gl_lds16(Wrow0 + 32, &Bs[1][l0]);
  gl_lds16(Wrow1 + 32, &Bs[1][l1]);

  int slot = 0;            // ring slot holding tile `it`
  for (int it = 0; it < nIter; ++it) {
    // wait until tile `it`'s 4 loads are done; tile it+1's may still fly
    if (it + 1 < nIter) {
      asm volatile("s_waitcnt vmcnt(4)" ::: "memory");
    } else {
      asm volatile("s_waitcnt vmcnt(0)" ::: "memory");
    }
    __builtin_amdgcn_s_barrier();
    // issue tile it+2 into the slot freed by tile it-1
    if (it + 2 < nIter) {
      int ns = slot + 2; if (ns >= 3) ns -= 3;
      const int kk = (it + 2) << 5;
      gl_lds16(Arow0 + kk, &As[ns][l0]);
      gl_lds16(Arow1 + kk, &As[ns][l1]);
      gl_lds16(Wrow0 + kk, &Bs[ns][l0]);
      gl_lds16(Wrow1 + kk, &Bs[ns][l1]);
    }
    // compute tile `it` (one live A-frag at a time to cap register pressure)
    const bf16_t* Ab = As[slot];
    const bf16_t* Bb = Bs[slot];
    bf16x8 bfr[4];
#pragma unroll
    for (int nt = 0; nt < 4; ++nt) bfr[nt] = *(const bf16x8*)(Bb + bOff[nt]);
#pragma unroll
    for (int mt = 0; mt < 4; ++mt) {
      bf16x8 af = *(const bf16x8*)(Ab + aOff[mt]);
#pragma unroll
      for (int nt = 0; nt < 4; ++nt)
        acc[mt][nt] = __builtin_amdgcn_mfma_f32_16x16x32_bf16(af, bfr[nt], acc[mt][nt], 0, 0, 0);
    }
    ++slot; if (slot >= 3) slot = 0;
  }

  // ---- epilogue ----
  // C/D layout: col = lane&15, row = quad*4 + reg  [verified m89/m91]
#pragma unroll
  for (int mt = 0; mt < 4; ++mt) {
#pragma unroll
    for (int nt = 0; nt < 4; ++nt) {
#pragma unroll
      for (int rg = 0; rg < 4; ++rg) {
        const int m = m0 + wm + mt * 16 + quad * 4 + rg;
        const int n = n0 + wn + nt * 16 + lrow;
        float v = acc[mt][nt][rg];
        const int p = n & 1;               // 0 = real component, 1 = imag

        if (MODE == 1) {
          const int cj = n & 1023;
          const int j = cj >> 1;
          const float bias = p ? (bx_im[region * 512 + j] + bh_im[region * 512 + j])
                               : (bx_re[region * 512 + j] + bh_re[region * 512 + j]);
          const float val = v + bias;
          if (region == 0) {               // z gate (bf16 store)
            zbuf[(size_t)m * 1024 + cj] = (bf16_t)fast_sigmoid(val);
          } else if (region == 1) {        // r gate -> rh = r * h (complex)
            float rv = fast_sigmoid(val);
            float ro = __shfl_xor(rv, 1, 64);
            float hp = p ? h_im[(size_t)m * 512 + j] : h_re[(size_t)m * 512 + j];
            float ho = __shfl_xor(hp, 1, 64);
            float rh = (p == 0) ? (rv * hp - ro * ho) : (ro * hp + rv * ho);
            A2[(size_t)m * 1024 + p * 512 + j] = (bf16_t)rh;
          } else {                         // px2 + bx2 + bh2 -> staged in d_out
            outbuf[(size_t)m * 1024 + cj] = val;
          }
        } else {
          // MODE 2: u = t + ph ; h_tilde = tanh(|u|)/|u| * u ; combine
          const int j = n >> 1;
          float t = outbuf[(size_t)m * 1024 + n];
          float u = t + v;
          float uo = __shfl_xor(u, 1, 64);
          float mag = sqrtf(u * u + uo * uo);
          float mm = fminf(mag, 20.0f);
          float e = __expf(2.0f * mm);
          float th = (e - 1.0f) / (e + 1.0f);
          float s = (mag == 0.0f) ? 0.0f : (th / mag);
          float hto = s * u;               // own component of h_tilde
          float htd = s * uo;              // other component
          float zv = (float)zbuf[(size_t)m * 1024 + n];
          float zo = __shfl_xor(zv, 1, 64);
          float hp = p ? h_im[(size_t)m * 512 + j] : h_re[(size_t)m * 512 + j];
          float ho = __shfl_xor(hp, 1, 64);
          float res;
          if (p == 0)
            res = (1.0f - zv) * hp + zo * ho + zv * hto - zo * htd;
          else
            res = (1.0f - zo) * hp - zv * ho + zo * hto + zv * htd;
          outbuf[(size_t)m * 1024 + n] = res;
        }
      }
    }
  }
}

// ---------------------------------------------------------------------------
extern "C" void kernel_launch(void* const* d_in, const int* in_sizes, int n_in,
                              void* d_out, int out_size, void* d_ws, size_t ws_size,
                              hipStream_t stream) {
  const float* x_re  = (const float*)d_in[0];
  const float* x_im  = (const float*)d_in[1];
  const float* h_re  = (const float*)d_in[2];
  const float* h_im  = (const float*)d_in[3];
  const float* Wx_re = (const float*)d_in[4];
  const float* Wx_im = (const float*)d_in[5];
  const float* Wh_re = (const float*)d_in[6];
  const float* Wh_im = (const float*)d_in[7];
  const float* bx_re = (const float*)d_in[8];
  const float* bx_im = (const float*)d_in[9];
  const float* bh_re = (const float*)d_in[10];
  const float* bh_im = (const float*)d_in[11];
  float* out = (float*)d_out;

  char* ws = (char*)d_ws;
  bf16_t* A_big = (bf16_t*)(ws);                         // 67108864 B
  bf16_t* W1t   = (bf16_t*)(ws + 67108864);              // 12582912 B
  bf16_t* W2t   = (bf16_t*)(ws + 79691776);              //  2097152 B
  bf16_t* A2    = (bf16_t*)(ws + 81788928);              // 33554432 B
  bf16_t* zbuf  = (bf16_t*)(ws + 115343360);             // 33554432 B  (end: 148897792)

  pack_A<<<32768, 256, 0, stream>>>(x_re, x_im, h_re, h_im, A_big);
  pack_W<<<6144, 256, 0, stream>>>(Wx_re, Wx_im, Wh_re, Wh_im, W1t, W2t);
  gemm_fused<1><<<128 * 24, 256, 0, stream>>>(A_big, W1t, 2048, 2048,
      zbuf, A2, out, h_re, h_im, bx_re, bx_im, bh_re, bh_im);
  gemm_fused<2><<<128 * 8, 256, 0, stream>>>(A2, W2t, 1024, 1024,
      zbuf, A2, out, h_re, h_im, bx_re, bx_im, bh_re, bh_im);
}